// Round 1
// baseline (1751.326 us; speedup 1.0000x reference)
//
#include <hip/hip_runtime.h>

static constexpr int kN  = 4096;   // nodes
static constexpr int kE  = 128;    // embed
static constexpr int kH  = 8;      // heads
static constexpr int kD  = 16;     // head dim
static constexpr int kNE = 65536;  // edges

// ---------------- Kernel 1: type-specific QKV projections ----------------
// grid kN, block kE(=128). y[n,f] = sum_e x[n,e]*W[t][e,f] + b[t][f]
__global__ void proj_kernel(const float* __restrict__ q_in, const float* __restrict__ k_in,
                            const float* __restrict__ v_in,
                            const float* __restrict__ Wq, const float* __restrict__ bq,
                            const float* __restrict__ Wk, const float* __restrict__ bk,
                            const float* __restrict__ Wv, const float* __restrict__ bv,
                            const int* __restrict__ node_types,
                            float* __restrict__ Q, float* __restrict__ K, float* __restrict__ V) {
    const int n = blockIdx.x;
    const int f = threadIdx.x;
    __shared__ float xq[kE], xk[kE], xv[kE];
    xq[f] = q_in[n * kE + f];
    xk[f] = k_in[n * kE + f];
    xv[f] = v_in[n * kE + f];
    __syncthreads();
    const int t = node_types[n];
    const float* wq = Wq + (size_t)t * kE * kE;
    const float* wk = Wk + (size_t)t * kE * kE;
    const float* wv = Wv + (size_t)t * kE * kE;
    float aq = bq[t * kE + f], ak = bk[t * kE + f], av = bv[t * kE + f];
#pragma unroll 8
    for (int e = 0; e < kE; ++e) {
        aq += xq[e] * wq[e * kE + f];
        ak += xk[e] * wk[e * kE + f];
        av += xv[e] * wv[e * kE + f];
    }
    Q[n * kE + f] = aq;
    K[n * kE + f] = ak;
    V[n * kE + f] = av;
}

// ---------------- Kernel 2: scores S[h,i,j] = Q.K/sqrt(D) ----------------
// grid (4, 32, 8): x = j-block of 1024, y = i-chunk of 128, z = head; block 256.
// Thread owns 4 consecutive j columns (K panel in registers), loops 128 i rows
// with Q broadcast from LDS. Writes float4, coalesced.
__global__ void scores_kernel(const float* __restrict__ Q, const float* __restrict__ K,
                              float* __restrict__ Sc) {
    const int j0 = blockIdx.x * 1024;
    const int i0 = blockIdx.y * 128;
    const int h  = blockIdx.z;
    const int t  = threadIdx.x;
    __shared__ float Qs[128][kD];  // 8 KB

    // K panel: 4 rows x 16 floats in registers
    float4 kr[4][4];
#pragma unroll
    for (int c = 0; c < 4; ++c) {
        const float* kp = K + (size_t)(j0 + t * 4 + c) * kE + h * kD;
#pragma unroll
        for (int q4 = 0; q4 < 4; ++q4) kr[c][q4] = ((const float4*)kp)[q4];
    }
    // stage Q chunk: 128 rows x 16 floats = 512 float4; 2 per thread
#pragma unroll
    for (int u = 0; u < 2; ++u) {
        int idx = t * 2 + u;
        int r = idx >> 2, c4 = idx & 3;
        ((float4*)&Qs[r][0])[c4] = ((const float4*)(Q + (size_t)(i0 + r) * kE + h * kD))[c4];
    }
    __syncthreads();

    float* out_base = Sc + ((size_t)h * kN + i0) * kN + j0 + t * 4;
#pragma unroll 2
    for (int ii = 0; ii < 128; ++ii) {
        float4 acc = {0.f, 0.f, 0.f, 0.f};
#pragma unroll
        for (int q4 = 0; q4 < 4; ++q4) {
            float4 qv = ((const float4*)&Qs[ii][0])[q4];  // wave-uniform broadcast
            acc.x += qv.x * kr[0][q4].x + qv.y * kr[0][q4].y + qv.z * kr[0][q4].z + qv.w * kr[0][q4].w;
            acc.y += qv.x * kr[1][q4].x + qv.y * kr[1][q4].y + qv.z * kr[1][q4].z + qv.w * kr[1][q4].w;
            acc.z += qv.x * kr[2][q4].x + qv.y * kr[2][q4].y + qv.z * kr[2][q4].z + qv.w * kr[2][q4].w;
            acc.w += qv.x * kr[3][q4].x + qv.y * kr[3][q4].y + qv.z * kr[3][q4].z + qv.w * kr[3][q4].w;
        }
        float4 res = {acc.x * 0.25f, acc.y * 0.25f, acc.z * 0.25f, acc.w * 0.25f};
        *((float4*)(out_base + (size_t)ii * kN)) = res;
    }
}

// ---------------- Kernel 3: edge-type bias scatter (dup-safe) ----------------
// grid kNE/256, block 256. scores[h, tgt, src] += edge_bias[et, h]
__global__ void edge_bias_kernel(const int* __restrict__ edge_index,
                                 const int* __restrict__ edge_types,
                                 const float* __restrict__ edge_bias,
                                 float* __restrict__ Sc) {
    const int e = blockIdx.x * 256 + threadIdx.x;
    const int src = edge_index[e];
    const int tgt = edge_index[kNE + e];
    const int et  = edge_types[e];
#pragma unroll
    for (int h = 0; h < kH; ++h) {
        atomicAdd(Sc + ((size_t)h * kN + tgt) * kN + src, edge_bias[et * kH + h]);
    }
}

// ---------------- Kernel 4: softmax (in place) + attn@V ----------------
// grid (kN/4, kH), block 256. S tile 4x4096 in LDS (row pad +8 to spread banks).
static constexpr int kSrow = kN + 8;
__global__ __launch_bounds__(256, 2) void softmax_pv_kernel(const float* __restrict__ V,
                                                            float* __restrict__ Sc,
                                                            float* __restrict__ OT) {
    const int i0 = blockIdx.x * 4;
    const int h  = blockIdx.y;
    const int t  = threadIdx.x;
    __shared__ float S[4][kSrow];      // ~64 KB
    __shared__ float inv_s[4];
    __shared__ float red[4][4][kD];    // (j-split, ii, d)

    float* gbase = Sc + ((size_t)h * kN + i0) * kN;
    // load 4 rows, coalesced float4
#pragma unroll
    for (int r = 0; r < 4; ++r) {
        const float4* grow = (const float4*)(gbase + (size_t)r * kN);
        float4* srow = (float4*)&S[r][0];
#pragma unroll
        for (int k = 0; k < 4; ++k) srow[k * 256 + t] = grow[k * 256 + t];
    }
    __syncthreads();

    // wave w owns row w
    const int w = t >> 6, lane = t & 63;
    {
        float m = -3.4e38f;
        for (int k = 0; k < 64; ++k) m = fmaxf(m, S[w][k * 64 + lane]);
#pragma unroll
        for (int off = 32; off > 0; off >>= 1) m = fmaxf(m, __shfl_xor(m, off, 64));
        float sum = 0.f;
        for (int k = 0; k < 16; ++k) {
            float4 sv = ((float4*)&S[w][0])[k * 64 + lane];
            sv.x = __expf(sv.x - m); sv.y = __expf(sv.y - m);
            sv.z = __expf(sv.z - m); sv.w = __expf(sv.w - m);
            ((float4*)&S[w][0])[k * 64 + lane] = sv;  // keep unnormalized e in LDS
            sum += sv.x + sv.y + sv.z + sv.w;
        }
#pragma unroll
        for (int off = 32; off > 0; off >>= 1) sum += __shfl_xor(sum, off, 64);
        const float inv = 1.f / sum;
        if (lane == 0) inv_s[w] = inv;
        // write normalized attn rows (coalesced float4)
        float4* grow = (float4*)(gbase + (size_t)w * kN);
        for (int k = 0; k < 16; ++k) {
            float4 ev = ((float4*)&S[w][0])[k * 64 + lane];
            float4 pv = {ev.x * inv, ev.y * inv, ev.z * inv, ev.w * inv};
            grow[k * 64 + lane] = pv;
        }
    }
    __syncthreads();

    // PV: 256 threads = 4 j-splits x 4 ii x 16 d
    {
        const int s  = t >> 6;        // wave-uniform split
        const int ii = (t >> 4) & 3;
        const int d  = t & 15;
        const float* vp = V + h * kD + d;
        const int jbase = s * 1024;
        float acc = 0.f;
#pragma unroll 8
        for (int j = 0; j < 1024; ++j) {
            acc += S[ii][jbase + j] * vp[(size_t)(jbase + j) * kE];
        }
        red[s][ii][d] = acc;
    }
    __syncthreads();
    if (t < 64) {
        const int ii = t >> 4, d = t & 15;
        float r = (red[0][ii][d] + red[1][ii][d] + red[2][ii][d] + red[3][ii][d]) * inv_s[ii];
        OT[(size_t)(i0 + ii) * kE + h * kD + d] = r;
    }
}

// ---------------- Kernel 5: output projection ----------------
// grid kN, block kE. out[n,f] = sum_e OT[n,e]*Wo[e,f] + bo[f]
__global__ void out_proj_kernel(const float* __restrict__ OT, const float* __restrict__ Wo,
                                const float* __restrict__ bo, float* __restrict__ out) {
    const int n = blockIdx.x, f = threadIdx.x;
    __shared__ float x[kE];
    x[f] = OT[n * kE + f];
    __syncthreads();
    float a = bo[f];
#pragma unroll 8
    for (int e = 0; e < kE; ++e) a += x[e] * Wo[e * kE + f];
    out[n * kE + f] = a;
}

extern "C" void kernel_launch(void* const* d_in, const int* in_sizes, int n_in,
                              void* d_out, int out_size, void* d_ws, size_t ws_size,
                              hipStream_t stream) {
    const float* query = (const float*)d_in[0];
    const float* key_  = (const float*)d_in[1];
    const float* value = (const float*)d_in[2];
    const float* Wq    = (const float*)d_in[3];
    const float* bq    = (const float*)d_in[4];
    const float* Wk    = (const float*)d_in[5];
    const float* bk    = (const float*)d_in[6];
    const float* Wv    = (const float*)d_in[7];
    const float* bv    = (const float*)d_in[8];
    const float* ebias = (const float*)d_in[9];
    const float* Wo    = (const float*)d_in[10];
    const float* bo    = (const float*)d_in[11];
    const int* node_types = (const int*)d_in[12];
    const int* edge_index = (const int*)d_in[13];
    const int* edge_types = (const int*)d_in[14];

    float* out = (float*)d_out;
    float* Sc  = (float*)d_out + (size_t)kN * kE;  // attn region; also scores scratch

    float* ws = (float*)d_ws;
    float* Q  = ws;                       // [N,E]
    float* K  = ws + (size_t)kN * kE;     // [N,E]
    float* V  = ws + 2 * (size_t)kN * kE; // [N,E]
    float* OT = Q;                        // reuse Q's buffer after scores_kernel

    proj_kernel<<<kN, kE, 0, stream>>>(query, key_, value, Wq, bq, Wk, bk, Wv, bv,
                                       node_types, Q, K, V);
    scores_kernel<<<dim3(4, 32, kH), 256, 0, stream>>>(Q, K, Sc);
    edge_bias_kernel<<<kNE / 256, 256, 0, stream>>>(edge_index, edge_types, ebias, Sc);
    softmax_pv_kernel<<<dim3(kN / 4, kH), 256, 0, stream>>>(V, Sc, OT);
    out_proj_kernel<<<kN, kE, 0, stream>>>(OT, Wo, bo, out);
}